// Round 8
// baseline (207.693 us; speedup 1.0000x reference)
//
#include <hip/hip_runtime.h>
#include <hip/hip_cooperative_groups.h>

namespace cg = cooperative_groups;

// SpatialMTP1Hop, single cooperative kernel (R8).
//   err_node[n] = mean_j (H[n]·W[:,j] + b[j] - target[n][j])^2
//   owner(s): fast path s<C (centers==arange, validated); general path via
//     scatter-only arr_idx + read-time check centers[arr_idx[s]]==s (race-free,
//     no sentinel init, poison-immune).
//   per masked edge (s,d): bucket owner(s)>>8 collects (o&255,d) pairs;
//   per-bucket LDS u64 fixed-point reduce; out = mean_c errsum/max(cnt,1).
//
// R7 lesson: kernel work is ~17-19us but 4 stream-ordered dispatches cost
// ~22us of graph gaps. R8: ONE dispatch + 2 grid.sync()s.

#define CNT_SHIFT 44
#define ERR_SCALE 67108864.0f     // 2^26 fixed-point for err
#define BKT_SHIFT 8
#define BKT_SIZE  256
#define CAP       8192            // slots/bucket (expected ~4080)
#define GBLK      768             // 3 blocks/CU on 256 CUs — co-residency safe
#define BTHR      256
#define P2B       256             // blocks participating in bucketize

__device__ __forceinline__ int owner_fn(int s, bool fast, int C,
                                        const int* __restrict__ arr_idx,
                                        const int* __restrict__ centers) {
    if (fast) return (s < C) ? s : -1;
    int i = arr_idx[s];
    return ((unsigned)i < (unsigned)C && centers[i] == s) ? i : -1;
}

__global__ __launch_bounds__(BTHR)
void fused_all(const float* __restrict__ H, const float* __restrict__ W,
               const float* __restrict__ b, const float* __restrict__ target,
               const int* __restrict__ eidx, const int* __restrict__ centers,
               float* __restrict__ err_node, int* __restrict__ arr_idx,
               unsigned int* __restrict__ gcursor, int* __restrict__ flag,
               unsigned int* __restrict__ pairs, float* __restrict__ out,
               int N, int E, int C, int NB, int out_size) {
    __shared__ unsigned int hist[256];
    __shared__ unsigned int base[256];
    __shared__ unsigned long long bins[256];
    __shared__ float wsum[BTHR / 64];

    cg::grid_group grid = cg::this_grid();
    const int t    = threadIdx.x;
    const int gtid = blockIdx.x * BTHR + t;
    const int gsz  = gridDim.x * BTHR;

    // ---------- Phase 0: inits + center scatter + arange validation ----------
    if (gtid < NB) gcursor[gtid] = 0u;
    if (gtid == 0) *flag = 1;
    if (gtid < out_size) out[gtid] = 0.f;
    bool mism = false;
    for (int i = gtid; i < C; i += gsz) {
        int c = centers[i];
        arr_idx[c] = i;                    // scatter-only: no sentinel, no race
        mism |= (c != i);
    }
    if (__ballot(mism) != 0ull && (t & 63) == 0) atomicAnd(flag, 0);

    // ---------- Phase 1: err_node (32 lanes/node, 2 nodes/wave, 2-deep) ----------
    {
        const int lane = t & 63;
        const int sub  = lane >> 5;
        const int l32  = lane & 31;
        float wr[12];
        {
            const float* wb = W + (size_t)(4 * l32) * 3;
            #pragma unroll
            for (int r = 0; r < 12; ++r) wr[r] = wb[r];
        }
        const float4* H4 = reinterpret_cast<const float4*>(H);
        const int wave  = blockIdx.x * (BTHR >> 6) + (t >> 6);
        const int nw    = gridDim.x * (BTHR >> 6);
        const int npair = (N + 1) >> 1;
        for (int p = wave; p < npair; p += 2 * nw) {
            const int pB  = p + nw;
            const int nA  = 2 * p + sub;
            const int nB_ = 2 * pB + sub;
            float4 hA = (nA < N) ? H4[(size_t)nA * 32 + l32]
                                 : make_float4(0.f, 0.f, 0.f, 0.f);
            float4 hB = (pB < npair && nB_ < N) ? H4[(size_t)nB_ * 32 + l32]
                                 : make_float4(0.f, 0.f, 0.f, 0.f);
            // --- A ---
            {
                float hx[4] = {hA.x, hA.y, hA.z, hA.w};
                float a0 = 0.f, a1 = 0.f, a2 = 0.f;
                #pragma unroll
                for (int r = 0; r < 4; ++r) {
                    a0 += hx[r] * wr[r * 3 + 0];
                    a1 += hx[r] * wr[r * 3 + 1];
                    a2 += hx[r] * wr[r * 3 + 2];
                }
                #pragma unroll
                for (int m = 16; m > 0; m >>= 1) {
                    a0 += __shfl_xor(a0, m, 64);
                    a1 += __shfl_xor(a1, m, 64);
                    a2 += __shfl_xor(a2, m, 64);
                }
                if (l32 == 0 && nA < N) {
                    float e0 = a0 + b[0] - target[(size_t)nA * 3 + 0];
                    float e1 = a1 + b[1] - target[(size_t)nA * 3 + 1];
                    float e2 = a2 + b[2] - target[(size_t)nA * 3 + 2];
                    err_node[nA] = (e0*e0 + e1*e1 + e2*e2) * (1.0f / 3.0f);
                }
            }
            // --- B ---
            if (pB < npair) {
                float hx[4] = {hB.x, hB.y, hB.z, hB.w};
                float a0 = 0.f, a1 = 0.f, a2 = 0.f;
                #pragma unroll
                for (int r = 0; r < 4; ++r) {
                    a0 += hx[r] * wr[r * 3 + 0];
                    a1 += hx[r] * wr[r * 3 + 1];
                    a2 += hx[r] * wr[r * 3 + 2];
                }
                #pragma unroll
                for (int m = 16; m > 0; m >>= 1) {
                    a0 += __shfl_xor(a0, m, 64);
                    a1 += __shfl_xor(a1, m, 64);
                    a2 += __shfl_xor(a2, m, 64);
                }
                if (l32 == 0 && nB_ < N) {
                    float e0 = a0 + b[0] - target[(size_t)nB_ * 3 + 0];
                    float e1 = a1 + b[1] - target[(size_t)nB_ * 3 + 1];
                    float e2 = a2 + b[2] - target[(size_t)nB_ * 3 + 2];
                    err_node[nB_] = (e0*e0 + e1*e1 + e2*e2) * (1.0f / 3.0f);
                }
            }
        }
    }
    grid.sync();

    // ---------- Phase 2: bucketize (blocks 0..P2B-1), two-pass, 2KB LDS ----------
    const bool fast = (*flag != 0);
    if (blockIdx.x < P2B) {
        const int E4    = E >> 2;           // (E&3)==0 guaranteed by host gate
        const int chunk = (E4 + P2B - 1) / P2B;
        const int c0    = blockIdx.x * chunk;
        const int c1    = min(E4, c0 + chunk);
        hist[t] = 0u;
        __syncthreads();
        const int4* r0 = reinterpret_cast<const int4*>(eidx);
        const int4* r1 = reinterpret_cast<const int4*>(eidx + E);
        for (int i = c0 + t; i < c1; i += BTHR) {
            int4 s4 = r0[i];
            int ss[4] = {s4.x, s4.y, s4.z, s4.w};
            #pragma unroll
            for (int k = 0; k < 4; ++k) {
                int o = owner_fn(ss[k], fast, C, arr_idx, centers);
                if (o >= 0) atomicAdd(&hist[(unsigned)o >> BKT_SHIFT], 1u);
            }
        }
        __syncthreads();
        {
            unsigned int h = hist[t];       // buckets >= NB are always 0
            base[t] = h ? atomicAdd(&gcursor[t], h) : 0u;
            hist[t] = 0u;                   // reuse as local cursor
        }
        __syncthreads();
        for (int i = c0 + t; i < c1; i += BTHR) {
            int4 s4 = r0[i];
            int4 d4 = r1[i];
            int ss[4] = {s4.x, s4.y, s4.z, s4.w};
            int dd[4] = {d4.x, d4.y, d4.z, d4.w};
            #pragma unroll
            for (int k = 0; k < 4; ++k) {
                int o = owner_fn(ss[k], fast, C, arr_idx, centers);
                if (o >= 0) {
                    unsigned int bk = (unsigned)o >> BKT_SHIFT;
                    unsigned int slot = base[bk] + atomicAdd(&hist[bk], 1u);
                    if (slot < CAP)
                        pairs[(size_t)bk * CAP + slot] =
                            (((unsigned)o & (BKT_SIZE - 1)) << 17) | (unsigned)dd[k];
                }
            }
        }
    }
    grid.sync();

    // ---------- Phase 3: per-bucket LDS u64 reduce + grand mean ----------
    if (blockIdx.x < NB) {
        const int bk = blockIdx.x;
        bins[t] = 0ull;
        __syncthreads();
        unsigned int count = gcursor[bk];
        if (count > CAP) count = CAP;
        for (unsigned int i = t; i < count; i += BTHR) {
            unsigned int p = pairs[(size_t)bk * CAP + i];
            float err = err_node[p & 0x1FFFFu];
            atomicAdd(&bins[p >> 17],
                      (1ull << CNT_SHIFT) + (unsigned long long)(err * ERR_SCALE));
        }
        __syncthreads();
        float term = 0.f;
        {
            int center = bk * BKT_SIZE + t;
            if (center < C) {
                unsigned long long u = bins[t];
                float cnt = (float)(u >> CNT_SHIFT);
                float es  = (float)(u & ((1ull << CNT_SHIFT) - 1)) * (1.0f / ERR_SCALE);
                term = es / fmaxf(cnt, 1.0f);
            }
        }
        #pragma unroll
        for (int m = 32; m > 0; m >>= 1) term += __shfl_down(term, m, 64);
        if ((t & 63) == 0) wsum[t >> 6] = term;
        __syncthreads();
        if (t == 0)
            atomicAdd(out, (wsum[0] + wsum[1] + wsum[2] + wsum[3]) / (float)C);
    }
}

// ================= fallback (non-coop, general shapes / small ws) =================
__global__ __launch_bounds__(256)
void fb_err_kernel(const float* __restrict__ H, const float* __restrict__ W,
                   const float* __restrict__ b, const float* __restrict__ target,
                   const int* __restrict__ centers,
                   float* __restrict__ err_node, int* __restrict__ arr_idx,
                   float* __restrict__ out, int N, int C, int D, int DO,
                   int out_size) {
    int gtid = blockIdx.x * blockDim.x + threadIdx.x;
    if (gtid < C) arr_idx[centers[gtid]] = gtid;
    if (gtid < out_size) out[gtid] = 0.f;
    // generic scalar err: one thread per node (D,DO general)
    if (gtid < N) {
        float acc = 0.f;
        for (int j = 0; j < DO; ++j) {
            float a = b[j];
            for (int r = 0; r < D; ++r) a += H[(size_t)gtid * D + r] * W[(size_t)r * DO + j];
            float e = a - target[(size_t)gtid * DO + j];
            acc += e * e;
        }
        err_node[gtid] = acc / (float)DO;
    }
}

__global__ void fb_edge_kernel(const int* __restrict__ eidx,
                               const int* __restrict__ arr_idx,
                               const int* __restrict__ centers,
                               const float* __restrict__ err_node,
                               unsigned long long* __restrict__ binsg,
                               int E, int C) {
    int e = blockIdx.x * blockDim.x + threadIdx.x;
    if (e >= E) return;
    int s = eidx[e];
    int o = owner_fn(s, false, C, arr_idx, centers);
    if (o >= 0) {
        int d = eidx[E + e];
        unsigned long long add = (1ull << CNT_SHIFT)
                               + (unsigned long long)(err_node[d] * ERR_SCALE);
        atomicAdd(&binsg[o], add);
    }
}

__global__ void fb_finalize_kernel(const unsigned long long* __restrict__ binsg,
                                   float* __restrict__ out, int C) {
    int i = blockIdx.x * blockDim.x + threadIdx.x;
    float term = 0.f;
    if (i < C) {
        unsigned long long u = binsg[i];
        float cnt = (float)(u >> CNT_SHIFT);
        float es  = (float)(u & ((1ull << CNT_SHIFT) - 1)) * (1.0f / ERR_SCALE);
        term = es / fmaxf(cnt, 1.0f);
    }
    #pragma unroll
    for (int m = 32; m > 0; m >>= 1) term += __shfl_down(term, m, 64);
    __shared__ float wsum[4];
    if ((threadIdx.x & 63) == 0) wsum[threadIdx.x >> 6] = term;
    __syncthreads();
    if (threadIdx.x == 0)
        atomicAdd(out, (wsum[0] + wsum[1] + wsum[2] + wsum[3]) / (float)C);
}

extern "C" void kernel_launch(void* const* d_in, const int* in_sizes, int n_in,
                              void* d_out, int out_size, void* d_ws, size_t ws_size,
                              hipStream_t stream) {
    const float* H      = (const float*)d_in[0];
    const float* W      = (const float*)d_in[1];
    const float* b      = (const float*)d_in[2];
    const float* target = (const float*)d_in[3];
    const int*   eidx   = (const int*)d_in[4];
    const int*   ctrs   = (const int*)d_in[5];

    const int DO = in_sizes[2];
    const int D  = in_sizes[1] / DO;     // 128
    const int N  = in_sizes[0] / D;      // 100000
    const int E  = in_sizes[4] / 2;      // 1600000
    const int C  = in_sizes[5];          // 50000
    const int NB = (C + BKT_SIZE - 1) >> BKT_SHIFT;   // 196

    size_t off = 0;
    auto take = [&](size_t bytes) {
        void* p = (char*)d_ws + off;
        off = (off + bytes + 255) & ~255ull;
        return p;
    };
    float*        err_node = (float*)take((size_t)N * 4);
    int*          arr_idx  = (int*)take((size_t)N * 4);
    unsigned int* gcursor  = (unsigned int*)take((size_t)NB * 4 + 1024);
    int*          flag     = (int*)take(256);
    unsigned int* pairs    = (unsigned int*)((char*)d_ws + off);
    size_t need = off + (size_t)NB * CAP * 4;

    bool fits = (ws_size >= need) && (NB <= 256) && (N < (1 << 17)) &&
                ((E & 3) == 0) && (D == 128) && (DO == 3);
    if (fits) {
        const float* H_ = H; const float* W_ = W; const float* b_ = b;
        const float* tg = target; const int* ei = eidx; const int* ct = ctrs;
        float* en = err_node; int* ai = arr_idx; unsigned int* gc = gcursor;
        int* fl = flag; unsigned int* pr = pairs; float* ou = (float*)d_out;
        int N_ = N, E_ = E, C_ = C, NB_ = NB, os = out_size;
        void* args[] = {&H_, &W_, &b_, &tg, &ei, &ct, &en, &ai, &gc, &fl,
                        &pr, &ou, &N_, &E_, &C_, &NB_, &os};
        hipLaunchCooperativeKernel((const void*)fused_all, dim3(GBLK),
                                   dim3(BTHR), args, 0, stream);
    } else {
        // general fallback: 3 plain launches + one memset (capture-legal)
        unsigned long long* binsg = (unsigned long long*)((char*)d_ws + off);
        hipMemsetAsync(binsg, 0, (size_t)C * 8, stream);
        int thr = 256;
        fb_err_kernel<<<(max(N, C) + thr - 1) / thr, thr, 0, stream>>>(
            H, W, b, target, ctrs, err_node, arr_idx, (float*)d_out,
            N, C, D, DO, out_size);
        fb_edge_kernel<<<(E + thr - 1) / thr, thr, 0, stream>>>(
            eidx, arr_idx, ctrs, err_node, binsg, E, C);
        fb_finalize_kernel<<<(C + thr - 1) / thr, thr, 0, stream>>>(
            binsg, (float*)d_out, C);
    }
}

// Round 9
// 43.646 us; speedup vs baseline: 4.7585x; 4.7585x over previous
//
#include <hip/hip_runtime.h>

// SpatialMTP1Hop (R9): 3 dispatches, err_node and bucketize fused into one
// kernel on disjoint block ranges (they're data-independent; overlap BW-bound
// err with atomic-bound bucketize).
//   err_node[n] = mean_j (H[n]·W[:,j] + b[j] - target[n][j])^2
//   owner(s): fast path s<C (centers==arange, validated via flagpart[]);
//     general path arr_idx + read-time check centers[arr_idx[s]]==s
//     (scatter-only, no sentinel, poison-immune).
//   per masked edge (s,d): bucket o>>8 collects (o&255,d) pairs;
//   per-bucket LDS u64 fixed-point reduce (exact); out=mean_c errsum/max(cnt,1).
//
// R8 lesson: cg::grid.sync() costs ~80-90us/sync on gfx950 (cross-XCD flush).
// Fuse only independent phases; keep stream ordering for true dependencies.

#define CNT_SHIFT 44
#define ERR_SCALE 67108864.0f     // 2^26 fixed-point for err
#define BKT_SHIFT 8
#define BKT_SIZE  256
#define CAP       8192            // slots/bucket (expected ~4080)
#define P2B       256             // bucketize blocks in D2
#define ERRB      640             // err_node blocks in D2
#define BTHR      256

__device__ __forceinline__ int owner_fn(int s, bool fast, int C,
                                        const int* __restrict__ arr_idx,
                                        const int* __restrict__ centers) {
    if (fast) return (s < C) ? s : -1;
    int i = arr_idx[s];
    return ((unsigned)i < (unsigned)C && centers[i] == s) ? i : -1;
}

// D1: center scatter + per-block arange validation + gcursor/out zeroing.
// flagpart[bid] written unconditionally -> no init needed, no race.
__global__ __launch_bounds__(BTHR)
void prep_kernel(const int* __restrict__ centers,
                 int* __restrict__ arr_idx,
                 int* __restrict__ flagpart,
                 unsigned int* __restrict__ gcursor,
                 float* __restrict__ out,
                 int C, int out_size) {
    __shared__ int ok;
    int t = threadIdx.x;
    int gtid = blockIdx.x * BTHR + t;
    if (t == 0) ok = 1;
    __syncthreads();
    bool mism = false;
    if (gtid < C) {
        int c = centers[gtid];
        arr_idx[c] = gtid;                 // scatter-only
        mism = (c != gtid);
    }
    if (__ballot(mism) != 0ull && (t & 63) == 0) atomicAnd(&ok, 0);
    __syncthreads();
    if (t == 0) flagpart[blockIdx.x] = ok;
    if (gtid < 256) gcursor[gtid] = 0u;
    if (gtid < out_size) out[gtid] = 0.f;
}

// D2: blocks [0,P2B): bucketize; blocks [P2B, P2B+ERRB): err_node.
__global__ __launch_bounds__(BTHR)
void mid_kernel(const float* __restrict__ H, const float* __restrict__ W,
                const float* __restrict__ b, const float* __restrict__ target,
                const int* __restrict__ eidx, const int* __restrict__ centers,
                const int* __restrict__ arr_idx,
                const int* __restrict__ flagpart,
                float* __restrict__ err_node,
                unsigned int* __restrict__ gcursor,
                unsigned int* __restrict__ pairs,
                int N, int E, int C, int NBV) {
    const int t = threadIdx.x;

    if (blockIdx.x < P2B) {
        // ---------------- bucketize ----------------
        __shared__ unsigned int hist[256];
        __shared__ unsigned int base[256];
        __shared__ int okflag;
        if (t == 0) okflag = 1;
        hist[t] = 0u;
        __syncthreads();
        bool my_ok = (t < NBV) ? (flagpart[t] != 0) : true;
        if (__ballot(!my_ok) != 0ull && (t & 63) == 0) atomicAnd(&okflag, 0);
        __syncthreads();
        const bool fast = (okflag != 0);

        const int E4    = E >> 2;          // (E&3)==0 gated on host
        const int chunk = (E4 + P2B - 1) / P2B;
        const int c0    = blockIdx.x * chunk;
        const int c1    = min(E4, c0 + chunk);
        const int4* r0 = reinterpret_cast<const int4*>(eidx);
        const int4* r1 = reinterpret_cast<const int4*>(eidx + E);

        for (int i = c0 + t; i < c1; i += BTHR) {
            int4 s4 = r0[i];
            int ss[4] = {s4.x, s4.y, s4.z, s4.w};
            #pragma unroll
            for (int k = 0; k < 4; ++k) {
                int o = owner_fn(ss[k], fast, C, arr_idx, centers);
                if (o >= 0) atomicAdd(&hist[(unsigned)o >> BKT_SHIFT], 1u);
            }
        }
        __syncthreads();
        {
            unsigned int h = hist[t];       // buckets >= NB always 0
            base[t] = h ? atomicAdd(&gcursor[t], h) : 0u;
            hist[t] = 0u;                   // reuse as local cursor
        }
        __syncthreads();
        for (int i = c0 + t; i < c1; i += BTHR) {
            int4 s4 = r0[i];
            int4 d4 = r1[i];
            int ss[4] = {s4.x, s4.y, s4.z, s4.w};
            int dd[4] = {d4.x, d4.y, d4.z, d4.w};
            #pragma unroll
            for (int k = 0; k < 4; ++k) {
                int o = owner_fn(ss[k], fast, C, arr_idx, centers);
                if (o >= 0) {
                    unsigned int bk = (unsigned)o >> BKT_SHIFT;
                    unsigned int slot = base[bk] + atomicAdd(&hist[bk], 1u);
                    if (slot < CAP)
                        pairs[(size_t)bk * CAP + slot] =
                            (((unsigned)o & (BKT_SIZE - 1)) << 17) | (unsigned)dd[k];
                }
            }
        }
    } else {
        // ---------------- err_node (4-deep grid-stride) ----------------
        const int lane = t & 63;
        const int sub  = lane >> 5;
        const int l32  = lane & 31;
        float wr[12];
        {
            const float* wb = W + (size_t)(4 * l32) * 3;
            #pragma unroll
            for (int r = 0; r < 12; ++r) wr[r] = wb[r];
        }
        const float b0 = b[0], b1 = b[1], b2 = b[2];
        const float4* H4 = reinterpret_cast<const float4*>(H);
        const int wv    = (blockIdx.x - P2B) * (BTHR >> 6) + (t >> 6);
        const int EW    = ERRB * (BTHR >> 6);
        const int npair = (N + 1) >> 1;

        for (int pb = wv; pb < npair; pb += 4 * EW) {
            float4 hv[4];
            int nd[4];
            #pragma unroll
            for (int k = 0; k < 4; ++k) {
                int p = pb + k * EW;
                nd[k] = (p < npair) ? (2 * p + sub) : N;
                hv[k] = (nd[k] < N) ? H4[(size_t)nd[k] * 32 + l32]
                                    : make_float4(0.f, 0.f, 0.f, 0.f);
            }
            #pragma unroll
            for (int k = 0; k < 4; ++k) {
                float hx[4] = {hv[k].x, hv[k].y, hv[k].z, hv[k].w};
                float a0 = 0.f, a1 = 0.f, a2 = 0.f;
                #pragma unroll
                for (int r = 0; r < 4; ++r) {
                    a0 += hx[r] * wr[r * 3 + 0];
                    a1 += hx[r] * wr[r * 3 + 1];
                    a2 += hx[r] * wr[r * 3 + 2];
                }
                #pragma unroll
                for (int m = 16; m > 0; m >>= 1) {
                    a0 += __shfl_xor(a0, m, 64);
                    a1 += __shfl_xor(a1, m, 64);
                    a2 += __shfl_xor(a2, m, 64);
                }
                if (l32 == 0 && nd[k] < N) {
                    float e0 = a0 + b0 - target[(size_t)nd[k] * 3 + 0];
                    float e1 = a1 + b1 - target[(size_t)nd[k] * 3 + 1];
                    float e2 = a2 + b2 - target[(size_t)nd[k] * 3 + 2];
                    err_node[nd[k]] = (e0*e0 + e1*e1 + e2*e2) * (1.0f / 3.0f);
                }
            }
        }
    }
}

// D3: per-bucket LDS u64 reduce + per-center mean + grand sum
__global__ __launch_bounds__(512)
void reduce_kernel(const unsigned int* __restrict__ pairs,
                   const unsigned int* __restrict__ gcursor,
                   const float* __restrict__ err_node,
                   float* __restrict__ out, int C, float invC) {
    __shared__ unsigned long long bins[BKT_SIZE];
    int bk = blockIdx.x, t = threadIdx.x;
    if (t < BKT_SIZE) bins[t] = 0ull;
    __syncthreads();
    unsigned int count = gcursor[bk];
    if (count > CAP) count = CAP;
    for (unsigned int i = t; i < count; i += 512) {
        unsigned int p = pairs[(size_t)bk * CAP + i];
        float err = err_node[p & 0x1FFFFu];
        atomicAdd(&bins[p >> 17],
                  (1ull << CNT_SHIFT) + (unsigned long long)(err * ERR_SCALE));
    }
    __syncthreads();
    float term = 0.f;
    if (t < BKT_SIZE) {
        int center = bk * BKT_SIZE + t;
        if (center < C) {
            unsigned long long u = bins[t];
            float cnt = (float)(u >> CNT_SHIFT);
            float es  = (float)(u & ((1ull << CNT_SHIFT) - 1)) * (1.0f / ERR_SCALE);
            term = es / fmaxf(cnt, 1.0f);
        }
    }
    #pragma unroll
    for (int m = 32; m > 0; m >>= 1) term += __shfl_down(term, m, 64);
    __shared__ float wsum[8];
    if ((t & 63) == 0) wsum[t >> 6] = term;
    __syncthreads();
    if (t == 0) {
        float s = 0.f;
        #pragma unroll
        for (int w = 0; w < 8; ++w) s += wsum[w];
        atomicAdd(out, s * invC);
    }
}

// ================= fallback (general shapes / small ws) =================
__global__ __launch_bounds__(256)
void fb_err_kernel(const float* __restrict__ H, const float* __restrict__ W,
                   const float* __restrict__ b, const float* __restrict__ target,
                   const int* __restrict__ centers,
                   float* __restrict__ err_node, int* __restrict__ arr_idx,
                   float* __restrict__ out, int N, int C, int D, int DO,
                   int out_size) {
    int gtid = blockIdx.x * blockDim.x + threadIdx.x;
    if (gtid < C) arr_idx[centers[gtid]] = gtid;
    if (gtid < out_size) out[gtid] = 0.f;
    if (gtid < N) {
        float acc = 0.f;
        for (int j = 0; j < DO; ++j) {
            float a = b[j];
            for (int r = 0; r < D; ++r)
                a += H[(size_t)gtid * D + r] * W[(size_t)r * DO + j];
            float e = a - target[(size_t)gtid * DO + j];
            acc += e * e;
        }
        err_node[gtid] = acc / (float)DO;
    }
}

__global__ void fb_edge_kernel(const int* __restrict__ eidx,
                               const int* __restrict__ arr_idx,
                               const int* __restrict__ centers,
                               const float* __restrict__ err_node,
                               unsigned long long* __restrict__ binsg,
                               int E, int C) {
    int e = blockIdx.x * blockDim.x + threadIdx.x;
    if (e >= E) return;
    int s = eidx[e];
    int o = owner_fn(s, false, C, arr_idx, centers);
    if (o >= 0) {
        int d = eidx[E + e];
        unsigned long long add = (1ull << CNT_SHIFT)
                               + (unsigned long long)(err_node[d] * ERR_SCALE);
        atomicAdd(&binsg[o], add);
    }
}

__global__ void fb_finalize_kernel(const unsigned long long* __restrict__ binsg,
                                   float* __restrict__ out, int C) {
    int i = blockIdx.x * blockDim.x + threadIdx.x;
    float term = 0.f;
    if (i < C) {
        unsigned long long u = binsg[i];
        float cnt = (float)(u >> CNT_SHIFT);
        float es  = (float)(u & ((1ull << CNT_SHIFT) - 1)) * (1.0f / ERR_SCALE);
        term = es / fmaxf(cnt, 1.0f);
    }
    #pragma unroll
    for (int m = 32; m > 0; m >>= 1) term += __shfl_down(term, m, 64);
    __shared__ float wsum[4];
    if ((threadIdx.x & 63) == 0) wsum[threadIdx.x >> 6] = term;
    __syncthreads();
    if (threadIdx.x == 0)
        atomicAdd(out, (wsum[0] + wsum[1] + wsum[2] + wsum[3]) / (float)C);
}

extern "C" void kernel_launch(void* const* d_in, const int* in_sizes, int n_in,
                              void* d_out, int out_size, void* d_ws, size_t ws_size,
                              hipStream_t stream) {
    const float* H      = (const float*)d_in[0];
    const float* W      = (const float*)d_in[1];
    const float* b      = (const float*)d_in[2];
    const float* target = (const float*)d_in[3];
    const int*   eidx   = (const int*)d_in[4];
    const int*   ctrs   = (const int*)d_in[5];

    const int DO = in_sizes[2];
    const int D  = in_sizes[1] / DO;     // 128
    const int N  = in_sizes[0] / D;      // 100000
    const int E  = in_sizes[4] / 2;      // 1600000
    const int C  = in_sizes[5];          // 50000
    const int NB = (C + BKT_SIZE - 1) >> BKT_SHIFT;   // 196
    const int NBV = (C + BTHR - 1) / BTHR;            // prep blocks = 196

    size_t off = 0;
    auto take = [&](size_t bytes) {
        void* p = (char*)d_ws + off;
        off = (off + bytes + 255) & ~255ull;
        return p;
    };
    float*        err_node = (float*)take((size_t)N * 4);
    int*          arr_idx  = (int*)take((size_t)N * 4);
    unsigned int* gcursor  = (unsigned int*)take(256 * 4);
    int*          flagpart = (int*)take((size_t)NBV * 4);
    unsigned int* pairs    = (unsigned int*)((char*)d_ws + off);
    size_t need = off + (size_t)NB * CAP * 4;

    bool fits = (ws_size >= need) && (NB <= 256) && (NBV <= BTHR) &&
                (N < (1 << 17)) && ((E & 3) == 0) && (D == 128) && (DO == 3);
    if (fits) {
        prep_kernel<<<NBV, BTHR, 0, stream>>>(ctrs, arr_idx, flagpart,
                                              gcursor, (float*)d_out,
                                              C, out_size);
        mid_kernel<<<P2B + ERRB, BTHR, 0, stream>>>(H, W, b, target, eidx,
                                                    ctrs, arr_idx, flagpart,
                                                    err_node, gcursor, pairs,
                                                    N, E, C, NBV);
        reduce_kernel<<<NB, 512, 0, stream>>>(pairs, gcursor, err_node,
                                              (float*)d_out, C, 1.0f / (float)C);
    } else {
        unsigned long long* binsg = (unsigned long long*)((char*)d_ws + off);
        hipMemsetAsync(binsg, 0, (size_t)C * 8, stream);
        int thr = 256;
        fb_err_kernel<<<(max(N, C) + thr - 1) / thr, thr, 0, stream>>>(
            H, W, b, target, ctrs, err_node, arr_idx, (float*)d_out,
            N, C, D, DO, out_size);
        fb_edge_kernel<<<(E + thr - 1) / thr, thr, 0, stream>>>(
            eidx, arr_idx, ctrs, err_node, binsg, E, C);
        fb_finalize_kernel<<<(C + thr - 1) / thr, thr, 0, stream>>>(
            binsg, (float*)d_out, C);
    }
}

// Round 10
// 39.713 us; speedup vs baseline: 5.2298x; 1.0990x over previous
//
#include <hip/hip_runtime.h>

// SpatialMTP1Hop (R10): block-local counting sort for the edge phase.
//   err_node[n] = mean_j (H[n]·W[:,j] + b[j] - target[n][j])^2
//   owner(s): fast path s<C (centers==arange, validated via flagpart);
//     general path arr_idx + read-time check centers[arr_idx[s]]==s.
//   D2: blocks [0,256) bucket-sort their edge chunk IN LDS (hist -> prefix ->
//       scatter), write the 25KB region contiguously + u16 prefix table. No
//       global cursor atomics, no scattered global writes (R9's bucketize
//       scattered 4B stores over 6.4MB => ~60MB phantom RMW traffic).
//       blocks [256,1024) do err_node (R5's proven shape).
//   D3: per-bucket LDS u64 fixed-point reduce over 256 per-block segments.
// Exact integer accumulation -> deterministic.

#define CNT_SHIFT 44
#define ERR_SCALE 67108864.0f     // 2^26 fixed-point for err
#define BKT_SHIFT 8
#define BKT_SIZE  256
#define P2B       256             // bucketize blocks
#define ERRB      768             // err_node blocks
#define BTHR      512
#define STASH     6272            // u32 entries per block region (>= chunk edges)
#define PREF_STRIDE 200           // u16 slots per source block (NB+1 <= 200)

__device__ __forceinline__ int owner_fn(int s, bool fast, int C,
                                        const int* __restrict__ arr_idx,
                                        const int* __restrict__ centers) {
    if (fast) return (s < C) ? s : -1;
    int i = arr_idx[s];
    return ((unsigned)i < (unsigned)C && centers[i] == s) ? i : -1;
}

// D1: center scatter + per-block arange validation + out zeroing.
__global__ __launch_bounds__(256)
void prep_kernel(const int* __restrict__ centers,
                 int* __restrict__ arr_idx,
                 int* __restrict__ flagpart,
                 float* __restrict__ out,
                 int C, int out_size) {
    __shared__ int ok;
    int t = threadIdx.x;
    int gtid = blockIdx.x * 256 + t;
    if (t == 0) ok = 1;
    __syncthreads();
    bool mism = false;
    if (gtid < C) {
        int c = centers[gtid];
        arr_idx[c] = gtid;                 // scatter-only, no sentinel needed
        mism = (c != gtid);
    }
    if (__ballot(mism) != 0ull && (t & 63) == 0) atomicAnd(&ok, 0);
    __syncthreads();
    if (t == 0) flagpart[blockIdx.x] = ok;
    if (gtid < out_size) out[gtid] = 0.f;
}

// D2: blocks [0,P2B): LDS counting-sort bucketize; [P2B,P2B+ERRB): err_node.
__global__ __launch_bounds__(BTHR)
void mid_kernel(const float* __restrict__ H, const float* __restrict__ W,
                const float* __restrict__ b, const float* __restrict__ target,
                const int* __restrict__ eidx, const int* __restrict__ centers,
                const int* __restrict__ arr_idx,
                const int* __restrict__ flagpart,
                float* __restrict__ err_node,
                unsigned short* __restrict__ pref_g,
                unsigned int* __restrict__ pairs,
                int N, int E, int C, int NB, int NBV) {
    __shared__ unsigned int stash[STASH];
    __shared__ unsigned int hist[256];     // counts, then reused as cursor
    __shared__ unsigned int scan[256];
    __shared__ int okflag;
    const int t = threadIdx.x;

    if (blockIdx.x < P2B) {
        // ---------------- bucketize (block-local counting sort) ----------------
        if (t == 0) okflag = 1;
        if (t < 256) hist[t] = 0u;
        __syncthreads();
        bool my_ok = (t < NBV) ? (flagpart[t] != 0) : true;
        if (__ballot(!my_ok) != 0ull && (t & 63) == 0) atomicAnd(&okflag, 0);
        __syncthreads();
        const bool fast = (okflag != 0);

        const int E4     = E >> 2;                    // (E&3)==0 host-gated
        const int chunk4 = (E4 + P2B - 1) / P2B;
        const int c0     = blockIdx.x * chunk4;
        const int c1     = min(E4, c0 + chunk4);
        const int4* r0 = reinterpret_cast<const int4*>(eidx);
        const int4* r1 = reinterpret_cast<const int4*>(eidx + E);

        // pass 1: histogram
        for (int i = c0 + t; i < c1; i += BTHR) {
            int4 s4 = r0[i];
            int ss[4] = {s4.x, s4.y, s4.z, s4.w};
            #pragma unroll
            for (int k = 0; k < 4; ++k) {
                int o = owner_fn(ss[k], fast, C, arr_idx, centers);
                if (o >= 0) atomicAdd(&hist[(unsigned)o >> BKT_SHIFT], 1u);
            }
        }
        __syncthreads();
        // inclusive Hillis-Steele scan of hist[0..255] into scan[]
        if (t < 256) scan[t] = hist[t];
        __syncthreads();
        for (int off = 1; off < 256; off <<= 1) {
            unsigned v = 0;
            if (t < 256 && t >= off) v = scan[t - off];
            __syncthreads();
            if (t < 256 && t >= off) scan[t] += v;
            __syncthreads();
        }
        // exclusive prefix -> cursor (reuse hist); emit u16 prefix table
        if (t < 256) {
            unsigned pre = (t == 0) ? 0u : scan[t - 1];
            hist[t] = pre;
            if (t <= NB)
                pref_g[(size_t)blockIdx.x * PREF_STRIDE + t] = (unsigned short)pre;
        }
        __syncthreads();
        // pass 2: LDS scatter
        for (int i = c0 + t; i < c1; i += BTHR) {
            int4 s4 = r0[i];
            int4 d4 = r1[i];
            int ss[4] = {s4.x, s4.y, s4.z, s4.w};
            int dd[4] = {d4.x, d4.y, d4.z, d4.w};
            #pragma unroll
            for (int k = 0; k < 4; ++k) {
                int o = owner_fn(ss[k], fast, C, arr_idx, centers);
                if (o >= 0) {
                    unsigned bk = (unsigned)o >> BKT_SHIFT;
                    unsigned pos = atomicAdd(&hist[bk], 1u);
                    stash[pos] = (((unsigned)o & (BKT_SIZE - 1)) << 17)
                               | (unsigned)dd[k];
                }
            }
        }
        __syncthreads();
        // stream the whole region out, fully coalesced (tail entries = garbage,
        // never read: reduce only reads within [pref[bk], pref[bk+1]))
        uint4*       dg = reinterpret_cast<uint4*>(pairs + (size_t)blockIdx.x * STASH);
        const uint4* sg = reinterpret_cast<const uint4*>(stash);
        for (int i = t; i < STASH / 4; i += BTHR) dg[i] = sg[i];
    } else {
        // ---------------- err_node (R5's proven shape) ----------------
        const int lane = t & 63;
        const int sub  = lane >> 5;
        const int l32  = lane & 31;
        float wr[12];
        {
            const float* wb = W + (size_t)(4 * l32) * 3;
            #pragma unroll
            for (int r = 0; r < 12; ++r) wr[r] = wb[r];
        }
        const float b0 = b[0], b1 = b[1], b2 = b[2];
        const float4* H4 = reinterpret_cast<const float4*>(H);
        const int wv    = (blockIdx.x - P2B) * (BTHR >> 6) + (t >> 6);
        const int EW    = ERRB * (BTHR >> 6);
        const int npair = (N + 1) >> 1;
        for (int p = wv; p < npair; p += EW) {
            const int node = 2 * p + sub;
            float4 hv = (node < N) ? H4[(size_t)node * 32 + l32]
                                   : make_float4(0.f, 0.f, 0.f, 0.f);
            float hx[4] = {hv.x, hv.y, hv.z, hv.w};
            float a0 = 0.f, a1 = 0.f, a2 = 0.f;
            #pragma unroll
            for (int r = 0; r < 4; ++r) {
                a0 += hx[r] * wr[r * 3 + 0];
                a1 += hx[r] * wr[r * 3 + 1];
                a2 += hx[r] * wr[r * 3 + 2];
            }
            #pragma unroll
            for (int m = 16; m > 0; m >>= 1) {
                a0 += __shfl_xor(a0, m, 64);
                a1 += __shfl_xor(a1, m, 64);
                a2 += __shfl_xor(a2, m, 64);
            }
            if (l32 == 0 && node < N) {
                float e0 = a0 + b0 - target[(size_t)node * 3 + 0];
                float e1 = a1 + b1 - target[(size_t)node * 3 + 1];
                float e2 = a2 + b2 - target[(size_t)node * 3 + 2];
                err_node[node] = (e0*e0 + e1*e1 + e2*e2) * (1.0f / 3.0f);
            }
        }
    }
}

// D3: per-bucket reduce. Thread t owns source-block t's segment of bucket bk.
__global__ __launch_bounds__(256)
void reduce_kernel(const unsigned int* __restrict__ pairs,
                   const unsigned short* __restrict__ pref_g,
                   const float* __restrict__ err_node,
                   float* __restrict__ out, int C, float invC) {
    __shared__ unsigned long long bins[BKT_SIZE];
    __shared__ float wsum[4];
    const int bk = blockIdx.x, t = threadIdx.x;
    bins[t] = 0ull;
    __syncthreads();
    {
        const size_t pb = (size_t)t * PREF_STRIDE;
        unsigned start = pref_g[pb + bk];
        unsigned end   = pref_g[pb + bk + 1];
        const unsigned int* reg = pairs + (size_t)t * STASH;
        for (unsigned i = start; i < end; ++i) {
            unsigned p = reg[i];
            float err = err_node[p & 0x1FFFFu];
            atomicAdd(&bins[p >> 17],
                      (1ull << CNT_SHIFT) + (unsigned long long)(err * ERR_SCALE));
        }
    }
    __syncthreads();
    float term = 0.f;
    {
        int center = bk * BKT_SIZE + t;
        if (center < C) {
            unsigned long long u = bins[t];
            float cnt = (float)(u >> CNT_SHIFT);
            float es  = (float)(u & ((1ull << CNT_SHIFT) - 1)) * (1.0f / ERR_SCALE);
            term = es / fmaxf(cnt, 1.0f);
        }
    }
    #pragma unroll
    for (int m = 32; m > 0; m >>= 1) term += __shfl_down(term, m, 64);
    if ((t & 63) == 0) wsum[t >> 6] = term;
    __syncthreads();
    if (t == 0)
        atomicAdd(out, (wsum[0] + wsum[1] + wsum[2] + wsum[3]) * invC);
}

// ================= fallback (general shapes / small ws) =================
__global__ __launch_bounds__(256)
void fb_err_kernel(const float* __restrict__ H, const float* __restrict__ W,
                   const float* __restrict__ b, const float* __restrict__ target,
                   const int* __restrict__ centers,
                   float* __restrict__ err_node, int* __restrict__ arr_idx,
                   float* __restrict__ out, int N, int C, int D, int DO,
                   int out_size) {
    int gtid = blockIdx.x * blockDim.x + threadIdx.x;
    if (gtid < C) arr_idx[centers[gtid]] = gtid;
    if (gtid < out_size) out[gtid] = 0.f;
    if (gtid < N) {
        float acc = 0.f;
        for (int j = 0; j < DO; ++j) {
            float a = b[j];
            for (int r = 0; r < D; ++r)
                a += H[(size_t)gtid * D + r] * W[(size_t)r * DO + j];
            float e = a - target[(size_t)gtid * DO + j];
            acc += e * e;
        }
        err_node[gtid] = acc / (float)DO;
    }
}

__global__ void fb_edge_kernel(const int* __restrict__ eidx,
                               const int* __restrict__ arr_idx,
                               const int* __restrict__ centers,
                               const float* __restrict__ err_node,
                               unsigned long long* __restrict__ binsg,
                               int E, int C) {
    int e = blockIdx.x * blockDim.x + threadIdx.x;
    if (e >= E) return;
    int s = eidx[e];
    int o = owner_fn(s, false, C, arr_idx, centers);
    if (o >= 0) {
        int d = eidx[E + e];
        unsigned long long add = (1ull << CNT_SHIFT)
                               + (unsigned long long)(err_node[d] * ERR_SCALE);
        atomicAdd(&binsg[o], add);
    }
}

__global__ void fb_finalize_kernel(const unsigned long long* __restrict__ binsg,
                                   float* __restrict__ out, int C) {
    int i = blockIdx.x * blockDim.x + threadIdx.x;
    float term = 0.f;
    if (i < C) {
        unsigned long long u = binsg[i];
        float cnt = (float)(u >> CNT_SHIFT);
        float es  = (float)(u & ((1ull << CNT_SHIFT) - 1)) * (1.0f / ERR_SCALE);
        term = es / fmaxf(cnt, 1.0f);
    }
    #pragma unroll
    for (int m = 32; m > 0; m >>= 1) term += __shfl_down(term, m, 64);
    __shared__ float wsum[4];
    if ((threadIdx.x & 63) == 0) wsum[threadIdx.x >> 6] = term;
    __syncthreads();
    if (threadIdx.x == 0)
        atomicAdd(out, (wsum[0] + wsum[1] + wsum[2] + wsum[3]) / (float)C);
}

extern "C" void kernel_launch(void* const* d_in, const int* in_sizes, int n_in,
                              void* d_out, int out_size, void* d_ws, size_t ws_size,
                              hipStream_t stream) {
    const float* H      = (const float*)d_in[0];
    const float* W      = (const float*)d_in[1];
    const float* b      = (const float*)d_in[2];
    const float* target = (const float*)d_in[3];
    const int*   eidx   = (const int*)d_in[4];
    const int*   ctrs   = (const int*)d_in[5];

    const int DO = in_sizes[2];
    const int D  = in_sizes[1] / DO;     // 128
    const int N  = in_sizes[0] / D;      // 100000
    const int E  = in_sizes[4] / 2;      // 1600000
    const int C  = in_sizes[5];          // 50000
    const int NB  = (C + BKT_SIZE - 1) >> BKT_SHIFT;  // 196
    const int NBV = (C + 255) / 256;                  // prep blocks = 196

    size_t off = 0;
    auto take = [&](size_t bytes) {
        void* p = (char*)d_ws + off;
        off = (off + bytes + 255) & ~255ull;
        return p;
    };
    float*          err_node = (float*)take((size_t)N * 4);
    int*            arr_idx  = (int*)take((size_t)N * 4);
    int*            flagpart = (int*)take((size_t)NBV * 4);
    unsigned short* pref_g   = (unsigned short*)take((size_t)P2B * PREF_STRIDE * 2);
    unsigned int*   pairs    = (unsigned int*)((char*)d_ws + off);
    size_t need = off + (size_t)P2B * STASH * 4;

    bool fits = (ws_size >= need) && (NB + 1 <= PREF_STRIDE) && (NBV <= BTHR) &&
                (N < (1 << 17)) && ((E & 3) == 0) && (E <= P2B * STASH) &&
                (D == 128) && (DO == 3);
    if (fits) {
        prep_kernel<<<NBV, 256, 0, stream>>>(ctrs, arr_idx, flagpart,
                                             (float*)d_out, C, out_size);
        mid_kernel<<<P2B + ERRB, BTHR, 0, stream>>>(H, W, b, target, eidx,
                                                    ctrs, arr_idx, flagpart,
                                                    err_node, pref_g, pairs,
                                                    N, E, C, NB, NBV);
        reduce_kernel<<<NB, 256, 0, stream>>>(pairs, pref_g, err_node,
                                              (float*)d_out, C, 1.0f / (float)C);
    } else {
        unsigned long long* binsg = (unsigned long long*)((char*)d_ws + off);
        hipMemsetAsync(binsg, 0, (size_t)C * 8, stream);
        int thr = 256;
        fb_err_kernel<<<(max(N, C) + thr - 1) / thr, thr, 0, stream>>>(
            H, W, b, target, ctrs, err_node, arr_idx, (float*)d_out,
            N, C, D, DO, out_size);
        fb_edge_kernel<<<(E + thr - 1) / thr, thr, 0, stream>>>(
            eidx, arr_idx, ctrs, err_node, binsg, E, C);
        fb_finalize_kernel<<<(C + thr - 1) / thr, thr, 0, stream>>>(
            binsg, (float*)d_out, C);
    }
}